// Round 1
// 158.241 us; speedup vs baseline: 1.0404x; 1.0404x over previous
//
#include <hip/hip_runtime.h>
#include <hip/hip_bf16.h>

typedef __bf16 bf16x8 __attribute__((ext_vector_type(8)));
typedef float f32x4 __attribute__((ext_vector_type(4)));

#define B_ 4
#define L_ 2048
#define D_ 512
#define H_ 8

// async 16B global -> LDS (gfx950 global_load_lds_dwordx4)
__device__ __forceinline__ void gl16(const __bf16* g, __bf16* l) {
  __builtin_amdgcn_global_load_lds(
      (const __attribute__((address_space(1))) void*)g,
      (__attribute__((address_space(3))) void*)l, 16, 0, 0);
}

// f32 -> bf16 conversion + packing. vec8 regions:
// x[0,524288) wqkv[524288,622592) wu[622592,655360) wout[655360,688128)
// Also builds bcat[2048] = [b_qkv ; b_u] (f32) in block 0.
__global__ __launch_bounds__(256) void cvt_pack(
    const float* __restrict__ x, const float* __restrict__ wq,
    const float* __restrict__ wu, const float* __restrict__ wo,
    const float* __restrict__ bq, const float* __restrict__ bu,
    __bf16* __restrict__ xb, __bf16* __restrict__ wcat,
    __bf16* __restrict__ wob, float* __restrict__ bcat)
{
  const int idx8 = blockIdx.x * 256 + threadIdx.x;
  const float* src; __bf16* dst; size_t so, dof;
  if (idx8 < 524288)      { src = x;  dst = xb;   so = (size_t)idx8 * 8;            dof = so; }
  else if (idx8 < 622592) { src = wq; dst = wcat; so = (size_t)(idx8 - 524288) * 8; dof = so; }
  else if (idx8 < 655360) { src = wu; dst = wcat; so = (size_t)(idx8 - 622592) * 8; dof = so + 786432; }
  else                    { src = wo; dst = wob;  so = (size_t)(idx8 - 655360) * 8; dof = so; }
  const float4 lo = *(const float4*)(src + so);
  const float4 hi = *(const float4*)(src + so + 4);
  bf16x8 r;
  r[0] = (__bf16)lo.x; r[1] = (__bf16)lo.y; r[2] = (__bf16)lo.z; r[3] = (__bf16)lo.w;
  r[4] = (__bf16)hi.x; r[5] = (__bf16)hi.y; r[6] = (__bf16)hi.z; r[7] = (__bf16)hi.w;
  *(bf16x8*)(dst + dof) = r;
  if (blockIdx.x == 0) {
#pragma unroll
    for (int e = 0; e < 8; ++e) {
      const int col = threadIdx.x * 8 + e;
      bcat[col] = (col < 1536) ? bq[col] : bu[col - 1536];
    }
  }
}

// C[M,N] = A[M,K] @ W[N,K]^T + bias[N]; all-bf16 inputs, f32 accum, TOUT out.
// 128x128 tile, BK=32, global_load_lds width-16 staging (m97 structure).
template <typename TOUT>
__global__ __launch_bounds__(256) void gemm_async(
    const __bf16* __restrict__ A, const __bf16* __restrict__ W,
    const float* __restrict__ bias, TOUT* __restrict__ C,
    int M, int N, int K)
{
  __shared__ __bf16 lA[4096];   // 128 x 32
  __shared__ __bf16 lB[4096];
  const int t = threadIdx.x;
  const int lane = t & 63;
  const int wave = t >> 6;
  const int bm0 = blockIdx.x * 128;
  const int bn0 = blockIdx.y * 128;
  const int wm = (wave >> 1) * 64;
  const int wn = (wave & 1) * 64;

  f32x4 acc[4][4] = {};

  const __bf16* Ap0 = A + (size_t)(bm0 + (t >> 2)) * K + (t & 3) * 8;
  const __bf16* Bp0 = W + (size_t)(bn0 + (t >> 2)) * K + (t & 3) * 8;
  const size_t r64 = (size_t)64 * K;

  for (int k0 = 0; k0 < K; k0 += 32) {
    __syncthreads();             // prior frag reads done before overwrite
    gl16(Ap0 + k0,       lA + t * 8);
    gl16(Ap0 + r64 + k0, lA + (t + 256) * 8);
    gl16(Bp0 + k0,       lB + t * 8);
    gl16(Bp0 + r64 + k0, lB + (t + 256) * 8);
    __syncthreads();             // vmcnt drain: staged data visible

    const int r = lane & 15, q = lane >> 4;
    bf16x8 af[4], bfr[4];
#pragma unroll
    for (int mi = 0; mi < 4; ++mi) af[mi] = ((const bf16x8*)lA)[(wm + mi * 16 + r) * 4 + q];
#pragma unroll
    for (int ni = 0; ni < 4; ++ni) bfr[ni] = ((const bf16x8*)lB)[(wn + ni * 16 + r) * 4 + q];
#pragma unroll
    for (int mi = 0; mi < 4; ++mi)
#pragma unroll
      for (int ni = 0; ni < 4; ++ni)
        acc[mi][ni] = __builtin_amdgcn_mfma_f32_16x16x32_bf16(af[mi], bfr[ni], acc[mi][ni], 0, 0, 0);
  }

  // C/D layout: col=lane&15, row=(lane>>4)*4+reg  [green since r13]
  const int cc = lane & 15, cq = lane >> 4;
#pragma unroll
  for (int mi = 0; mi < 4; ++mi) {
#pragma unroll
    for (int ni = 0; ni < 4; ++ni) {
      const int gcol = bn0 + wn + ni * 16 + cc;
      const float bv = bias[gcol];
#pragma unroll
      for (int rr = 0; rr < 4; ++rr) {
        const int grow = bm0 + wm + mi * 16 + cq * 4 + rr;
        C[(size_t)grow * N + gcol] = (TOUT)(acc[mi][ni][rr] + bv);
      }
    }
  }
}

// Flash-style MFMA attention, rewritten:
//  - lK XOR-swizzled (byte ^= (row&7)<<4): kills the 16-way bank conflict on
//    the 128B-stride ds_read_b128 fragment reads (guide G4 pattern).
//  - Q fragments hoisted to registers (each wave needs only 2 bf16x8).
//  - Softmax fully in-register: S-fragment rows are q-indices, kv spans
//    nt (in-lane) x 16-lane shfl group -> 4x shfl_xor tree; running m/l/corr
//    per-lane in registers. No Ssh/pmax/psum/ms/corrs LDS, no t<64 serial.
//  - P bounce through LDS is WAVE-LOCAL (wave writes+reads its own 16 rows):
//    no barrier between P-write and PV (per-wave DS ordering).
//  - 2 barriers/tile (protecting cooperative K/V staging) instead of 7.
//  LDS: 8KB lK + 9KB lV + 9KB Pb = 26.6KB -> 6 blocks/CU (was 53KB -> 3).
#define SP 72
#define QS 2048
__global__ __launch_bounds__(256) void attn_tile(
    const __bf16* __restrict__ qu,   // [B*L][2048]  q|k|v|u
    __bf16* __restrict__ g)          // [B*L][512]
{
  const int qt = blockIdx.x, h = blockIdx.y, b = blockIdx.z;
  const int t = threadIdx.x;
  const int lane = t & 63;
  const int w = t >> 6;
  const int q0 = qt * 64, qmax = q0 + 63;
  const size_t bL = (size_t)b * L_;

  __shared__ __bf16 lK[4096];       // [64][64] bf16, XOR-swizzled rows
  __shared__ __bf16 lV[64 * SP];    // V^T: [d 64][key 64] stride 72
  __shared__ __bf16 Pb[64 * SP];    // P:   [q 64][key 64] stride 72 (wave-local)

  const int cq = lane >> 4, cc = lane & 15;

  // Q fragments in registers: A-operand rows = w*16+cc, k = cq*8 (+32)
  bf16x8 aq0, aq1;
  {
    const __bf16* qsrc = qu + (bL + q0 + w * 16 + cc) * QS + h * 64 + cq * 8;
    aq0 = *(const bf16x8*)qsrc;
    aq1 = *(const bf16x8*)(qsrc + 32);
  }

  float mreg[4], lreg[4];
#pragma unroll
  for (int rr = 0; rr < 4; ++rr) { mreg[rr] = -1e30f; lreg[rr] = 0.f; }
  f32x4 acc_o[4] = {};

  int clist[5]; int ncl = 0;
  clist[ncl++] = 0;
  if (qmax >= 64) clist[ncl++] = 64;
  {
    int lo = 1921 - q0; if (lo < 0) lo = 0; lo &= ~63;
    const int hik = min(qmax, 2048 - q0);
    for (int c = lo; c <= hik; c += 64)
      if (c >= 128) clist[ncl++] = c;
  }

  for (int ci = 0; ci < ncl; ++ci) {
    const int c0 = clist[ci];
    __syncthreads();   // prior tile's PV reads of lK/lV done before overwrite
    {  // stage K, swizzled rows: row*128B block, slot ^= (row&7)<<4
      const int row = t >> 2, gb = t & 3;
      const __bf16* src = qu + (bL + c0 + row) * QS + 512 + h * 64;
      bf16x8 k0 = *(const bf16x8*)(src + gb * 8);
      bf16x8 k1 = *(const bf16x8*)(src + gb * 8 + 32);
      char* lkb = (char*)lK;
      const int sw = (row & 7) << 4;
      *(bf16x8*)(lkb + ((row * 128 + gb * 16) ^ sw))      = k0;
      *(bf16x8*)(lkb + ((row * 128 + gb * 16 + 64) ^ sw)) = k1;
    }
    {  // stage V transposed (stride-72 rows: conflict-free)
      const int key = lane;
      const __bf16* src = qu + (bL + c0 + key) * QS + 1024 + h * 64 + w * 16;
      bf16x8 va = *(const bf16x8*)src;
      bf16x8 vb = *(const bf16x8*)(src + 8);
#pragma unroll
      for (int e = 0; e < 8; ++e) {
        lV[(w * 16 + e) * SP + key]     = va[e];
        lV[(w * 16 + 8 + e) * SP + key] = vb[e];
      }
    }
    __syncthreads();

    // QK^T in-register: s[nt] rows q = q0+w*16+cq*4+rr, col kv = c0+nt*16+cc
    f32x4 s[4];
    {
      const char* lkb = (const char*)lK;
#pragma unroll
      for (int nt = 0; nt < 4; ++nt) {
        const int krow = nt * 16 + cc;
        const int sw = (krow & 7) << 4;
        bf16x8 bk0 = *(const bf16x8*)(lkb + ((krow * 128 + cq * 16) ^ sw));
        bf16x8 bk1 = *(const bf16x8*)(lkb + ((krow * 128 + 64 + cq * 16) ^ sw));
        f32x4 a = {};
        a = __builtin_amdgcn_mfma_f32_16x16x32_bf16(aq0, bk0, a, 0, 0, 0);
        a = __builtin_amdgcn_mfma_f32_16x16x32_bf16(aq1, bk1, a, 0, 0, 0);
        s[nt] = a;
      }
    }

    // mask + scale in-register
#pragma unroll
    for (int nt = 0; nt < 4; ++nt) {
#pragma unroll
      for (int rr = 0; rr < 4; ++rr) {
        const int i = q0 + w * 16 + cq * 4 + rr;
        const int j = c0 + nt * 16 + cc;
        const int ij = i + j;
        const bool valid = (j <= i) &&
            ((ij >= 1984 && ij <= 2048) || (j <= 64 && ij <= 2048));
        s[nt][rr] = valid ? s[nt][rr] * 0.125f : -1e30f;
      }
    }

    // row max: in-lane over nt, then 16-lane shfl_xor tree
    f32x4 pm;
#pragma unroll
    for (int rr = 0; rr < 4; ++rr)
      pm[rr] = fmaxf(fmaxf(s[0][rr], s[1][rr]), fmaxf(s[2][rr], s[3][rr]));
#pragma unroll
    for (int m = 1; m < 16; m <<= 1) {
#pragma unroll
      for (int rr = 0; rr < 4; ++rr)
        pm[rr] = fmaxf(pm[rr], __shfl_xor(pm[rr], m, 64));
    }
    float corr[4];
#pragma unroll
    for (int rr = 0; rr < 4; ++rr) {
      const float nm = fmaxf(mreg[rr], pm[rr]);
      corr[rr] = __expf(mreg[rr] - nm);
      mreg[rr] = nm;
    }

    // P = exp(s - m): store bf16 to wave-local Pb rows, accumulate row sums
    f32x4 ps = {};
#pragma unroll
    for (int nt = 0; nt < 4; ++nt) {
#pragma unroll
      for (int rr = 0; rr < 4; ++rr) {
        const float p = __expf(s[nt][rr] - mreg[rr]);
        ps[rr] += p;
        Pb[(w * 16 + cq * 4 + rr) * SP + nt * 16 + cc] = (__bf16)p;
      }
    }
#pragma unroll
    for (int m = 1; m < 16; m <<= 1) {
#pragma unroll
      for (int rr = 0; rr < 4; ++rr)
        ps[rr] += __shfl_xor(ps[rr], m, 64);
    }
#pragma unroll
    for (int rr = 0; rr < 4; ++rr) lreg[rr] = lreg[rr] * corr[rr] + ps[rr];

    // PV: rescale acc (register corr), read own-wave P + shared V
    {
      bf16x8 pa0 = *(const bf16x8*)(Pb + (w * 16 + cc) * SP + cq * 8);
      bf16x8 pa1 = *(const bf16x8*)(Pb + (w * 16 + cc) * SP + 32 + cq * 8);
#pragma unroll
      for (int dt = 0; dt < 4; ++dt) {
#pragma unroll
        for (int rr = 0; rr < 4; ++rr) acc_o[dt][rr] *= corr[rr];
        bf16x8 vb0 = *(const bf16x8*)(lV + (dt * 16 + cc) * SP + cq * 8);
        bf16x8 vb1 = *(const bf16x8*)(lV + (dt * 16 + cc) * SP + 32 + cq * 8);
        acc_o[dt] = __builtin_amdgcn_mfma_f32_16x16x32_bf16(pa0, vb0, acc_o[dt], 0, 0, 0);
        acc_o[dt] = __builtin_amdgcn_mfma_f32_16x16x32_bf16(pa1, vb1, acc_o[dt], 0, 0, 0);
      }
    }
  }

  // epilogue: all state in registers
#pragma unroll
  for (int dt = 0; dt < 4; ++dt) {
#pragma unroll
    for (int rr = 0; rr < 4; ++rr) {
      const int row16 = cq * 4 + rr;
      const size_t qrow = bL + q0 + w * 16 + row16;
      const int d = dt * 16 + cc;
      const float o = acc_o[dt][rr] / fmaxf(lreg[rr], 1e-30f);
      const float uv = (float)qu[qrow * QS + 1536 + h * 64 + d];
      g[qrow * D_ + h * 64 + d] = (__bf16)(o / (1.f + __expf(-o)) * uv);
    }
  }
}

extern "C" void kernel_launch(void* const* d_in, const int* in_sizes, int n_in,
                              void* d_out, int out_size, void* d_ws, size_t ws_size,
                              hipStream_t stream) {
  const float* x     = (const float*)d_in[0];
  const float* w_qkv = (const float*)d_in[1];
  const float* b_qkv = (const float*)d_in[2];
  const float* w_u   = (const float*)d_in[3];
  const float* b_u   = (const float*)d_in[4];
  const float* w_out = (const float*)d_in[5];
  const float* b_out = (const float*)d_in[6];
  float* out = (float*)d_out;

  char* ws = (char*)d_ws;
  __bf16* xb   = (__bf16*)ws;                           //  8 MB
  __bf16* wcat = (__bf16*)(ws + 8388608);               //  2 MB [w_qkv;w_u]
  __bf16* wob  = (__bf16*)(ws + 10485760);              //  0.5 MB
  float*  bcat = (float*) (ws + 11010048);              //  8 KB
  __bf16* qu   = (__bf16*)(ws + 11018240);              // 32 MB [q|k|v|u]
  __bf16* gb   = (__bf16*)(ws + 44572672);              //  8 MB

  cvt_pack<<<dim3(2688), dim3(256), 0, stream>>>(
      x, w_qkv, w_u, w_out, b_qkv, b_u, xb, wcat, wob, bcat);
  gemm_async<__bf16><<<dim3(64, 16), dim3(256), 0, stream>>>(
      xb, wcat, bcat, qu, 8192, 2048, 512);
  attn_tile<<<dim3(L_ / 64, H_, B_), dim3(256), 0, stream>>>(qu, gb);
  gemm_async<float><<<dim3(64, 4), dim3(256), 0, stream>>>(
      gb, wob, b_out, out, 8192, 512, 512);
}

// Round 2
// 148.511 us; speedup vs baseline: 1.1086x; 1.0655x over previous
//
#include <hip/hip_runtime.h>
#include <hip/hip_bf16.h>

typedef __bf16 bf16x8 __attribute__((ext_vector_type(8)));
typedef float f32x4 __attribute__((ext_vector_type(4)));

#define B_ 4
#define L_ 2048
#define D_ 512
#define H_ 8

// async 16B global -> LDS (gfx950 global_load_lds_dwordx4)
__device__ __forceinline__ void gl16(const __bf16* g, __bf16* l) {
  __builtin_amdgcn_global_load_lds(
      (const __attribute__((address_space(1))) void*)g,
      (__attribute__((address_space(3))) void*)l, 16, 0, 0);
}

// f32 -> bf16 conversion + packing. vec8 regions:
// x[0,524288) wqkv[524288,622592) wu[622592,655360) wout[655360,688128)
// Also builds bcat[2048] = [b_qkv ; b_u] (f32) in block 0.
__global__ __launch_bounds__(256) void cvt_pack(
    const float* __restrict__ x, const float* __restrict__ wq,
    const float* __restrict__ wu, const float* __restrict__ wo,
    const float* __restrict__ bq, const float* __restrict__ bu,
    __bf16* __restrict__ xb, __bf16* __restrict__ wcat,
    __bf16* __restrict__ wob, float* __restrict__ bcat)
{
  const int idx8 = blockIdx.x * 256 + threadIdx.x;
  const float* src; __bf16* dst; size_t so, dof;
  if (idx8 < 524288)      { src = x;  dst = xb;   so = (size_t)idx8 * 8;            dof = so; }
  else if (idx8 < 622592) { src = wq; dst = wcat; so = (size_t)(idx8 - 524288) * 8; dof = so; }
  else if (idx8 < 655360) { src = wu; dst = wcat; so = (size_t)(idx8 - 622592) * 8; dof = so + 786432; }
  else                    { src = wo; dst = wob;  so = (size_t)(idx8 - 655360) * 8; dof = so; }
  const float4 lo = *(const float4*)(src + so);
  const float4 hi = *(const float4*)(src + so + 4);
  bf16x8 r;
  r[0] = (__bf16)lo.x; r[1] = (__bf16)lo.y; r[2] = (__bf16)lo.z; r[3] = (__bf16)lo.w;
  r[4] = (__bf16)hi.x; r[5] = (__bf16)hi.y; r[6] = (__bf16)hi.z; r[7] = (__bf16)hi.w;
  *(bf16x8*)(dst + dof) = r;
  if (blockIdx.x == 0) {
#pragma unroll
    for (int e = 0; e < 8; ++e) {
      const int col = threadIdx.x * 8 + e;
      bcat[col] = (col < 1536) ? bq[col] : bu[col - 1536];
    }
  }
}

// ---------------------------------------------------------------------------
// 256x256 deep-pipelined GEMM (8-phase family, T2+T3+T4+T5), plain HIP.
// C[M,N] = A[M,K] @ W[N,K]^T + bias[N], bf16 out. Requires M%256==0,
// N%256==0, K%64==0, K/64>=2. 512 threads = 8 waves (2 M x 4 N), per-wave
// output 128x64. LDS = 2 bufs x (A 32KB + B 32KB) = 128 KB (dynamic).
//
// Schedule per K-tile t (buf p = t&1), 4 phases:
//   entry: s_waitcnt vmcnt(8) [vmcnt(0) on last tile]; s_barrier   (RAW)
//   ph0: ds_read A[mi0-3]x2k (8 b128) + B[ni0-1]x2k (4); 16 MFMA (A03xB01)
//   ph1: ds_read B[ni2-3]x2k (4);                        16 MFMA (A03xB23)
//   ph2: ds_read A[mi4-7]x2k (8);                        16 MFMA (A47xB01)
//        s_waitcnt lgkmcnt(0); s_barrier                 (WAR: reads done)
//   ph3: stage tile t+2 -> buf[p] (8 x gl16);            16 MFMA (A47xB23)
// vmcnt never drains to 0 in the main loop: 16 loads in flight steady-state,
// tile t's 8 are the oldest -> vmcnt(8) at entry.
//
// LDS swizzle (T2): rows are 128B; fragment reads are 16 rows x same col ->
// 16-way bank conflict unswizzled. byte ^= (row&7)<<4 spreads the wave's 64
// b128 lanes uniformly over 32 banks (8/bank = minimum). global_load_lds
// writes linearly, so the GLOBAL source chunk is pre-permuted with the same
// involution: c_src = c ^ ((c>>3)&7) (rule: both-sides-or-neither).
// ---------------------------------------------------------------------------
__global__ __launch_bounds__(512, 2) void gemm256(
    const __bf16* __restrict__ A, const __bf16* __restrict__ W,
    const float* __restrict__ bias, __bf16* __restrict__ C,
    int M, int N, int K)
{
  extern __shared__ char smem[];
  const int t = threadIdx.x;
  const int lane = t & 63;
  const int wave = t >> 6;
  const int wm = (wave >> 2) * 128;
  const int wn = (wave & 3) * 64;
  const int bm0 = blockIdx.x * 256;
  const int bn0 = blockIdx.y * 256;
  const int r = lane & 15, q = lane >> 4;
  const int nt = K >> 6;

  // buf p: A at smem + p*32768, B at smem + 65536 + p*32768
  auto stage = [&](int kt, int p) {
#pragma unroll
    for (int j = 0; j < 4; ++j) {
      const int c = t + j * 512;            // 16B chunk id, 2048/op
      const int row = c >> 3;
      const int cs = (c & 7) ^ (row & 7);   // inverse-swizzled source slot
      gl16(A + (size_t)(bm0 + row) * K + kt * 64 + cs * 8,
           (__bf16*)(smem + p * 32768) + c * 8);
    }
#pragma unroll
    for (int j = 0; j < 4; ++j) {
      const int c = t + j * 512;
      const int row = c >> 3;
      const int cs = (c & 7) ^ (row & 7);
      gl16(W + (size_t)(bn0 + row) * K + kt * 64 + cs * 8,
           (__bf16*)(smem + 65536 + p * 32768) + c * 8);
    }
  };
  auto rdA = [&](int p, int mi, int ks) -> bf16x8 {
    const int row = wm + mi * 16 + r;
    const int byte = row * 128 + ((ks * 64 + q * 16) ^ ((row & 7) << 4));
    return *(const bf16x8*)(smem + p * 32768 + byte);
  };
  auto rdB = [&](int p, int ni, int ks) -> bf16x8 {
    const int row = wn + ni * 16 + r;
    const int byte = row * 128 + ((ks * 64 + q * 16) ^ ((row & 7) << 4));
    return *(const bf16x8*)(smem + 65536 + p * 32768 + byte);
  };

  f32x4 acc[8][4] = {};

  stage(0, 0);
  stage(1, 1);

  for (int kt = 0; kt < nt; ++kt) {
    const int p = kt & 1;
    // ---- entry: tile kt staged & visible (RAW) ----
    if (kt < nt - 1) asm volatile("s_waitcnt vmcnt(8)" ::: "memory");
    else             asm volatile("s_waitcnt vmcnt(0)" ::: "memory");
    __builtin_amdgcn_sched_barrier(0);
    __builtin_amdgcn_s_barrier();
    __builtin_amdgcn_sched_barrier(0);

    bf16x8 a03[4][2], a47[4][2], b01[2][2], b23[2][2];
    // ph0
#pragma unroll
    for (int mi = 0; mi < 4; ++mi) { a03[mi][0] = rdA(p, mi, 0); a03[mi][1] = rdA(p, mi, 1); }
#pragma unroll
    for (int ni = 0; ni < 2; ++ni) { b01[ni][0] = rdB(p, ni, 0); b01[ni][1] = rdB(p, ni, 1); }
    __builtin_amdgcn_s_setprio(1);
#pragma unroll
    for (int mi = 0; mi < 4; ++mi)
#pragma unroll
      for (int ni = 0; ni < 2; ++ni) {
        acc[mi][ni] = __builtin_amdgcn_mfma_f32_16x16x32_bf16(a03[mi][0], b01[ni][0], acc[mi][ni], 0, 0, 0);
        acc[mi][ni] = __builtin_amdgcn_mfma_f32_16x16x32_bf16(a03[mi][1], b01[ni][1], acc[mi][ni], 0, 0, 0);
      }
    __builtin_amdgcn_s_setprio(0);
    // ph1
#pragma unroll
    for (int ni = 0; ni < 2; ++ni) { b23[ni][0] = rdB(p, ni + 2, 0); b23[ni][1] = rdB(p, ni + 2, 1); }
    __builtin_amdgcn_s_setprio(1);
#pragma unroll
    for (int mi = 0; mi < 4; ++mi)
#pragma unroll
      for (int ni = 0; ni < 2; ++ni) {
        acc[mi][ni + 2] = __builtin_amdgcn_mfma_f32_16x16x32_bf16(a03[mi][0], b23[ni][0], acc[mi][ni + 2], 0, 0, 0);
        acc[mi][ni + 2] = __builtin_amdgcn_mfma_f32_16x16x32_bf16(a03[mi][1], b23[ni][1], acc[mi][ni + 2], 0, 0, 0);
      }
    __builtin_amdgcn_s_setprio(0);
    // ph2
#pragma unroll
    for (int mi = 0; mi < 4; ++mi) { a47[mi][0] = rdA(p, mi + 4, 0); a47[mi][1] = rdA(p, mi + 4, 1); }
    __builtin_amdgcn_s_setprio(1);
#pragma unroll
    for (int mi = 0; mi < 4; ++mi)
#pragma unroll
      for (int ni = 0; ni < 2; ++ni) {
        acc[mi + 4][ni] = __builtin_amdgcn_mfma_f32_16x16x32_bf16(a47[mi][0], b01[ni][0], acc[mi + 4][ni], 0, 0, 0);
        acc[mi + 4][ni] = __builtin_amdgcn_mfma_f32_16x16x32_bf16(a47[mi][1], b01[ni][1], acc[mi + 4][ni], 0, 0, 0);
      }
    __builtin_amdgcn_s_setprio(0);
    // ---- all buf[p] reads issued+retired (WAR) before ph3 overwrites ----
    asm volatile("s_waitcnt lgkmcnt(0)" ::: "memory");
    __builtin_amdgcn_sched_barrier(0);
    __builtin_amdgcn_s_barrier();
    __builtin_amdgcn_sched_barrier(0);
    // ph3
    if (kt + 2 < nt) stage(kt + 2, p);
    __builtin_amdgcn_s_setprio(1);
#pragma unroll
    for (int mi = 0; mi < 4; ++mi)
#pragma unroll
      for (int ni = 0; ni < 2; ++ni) {
        acc[mi + 4][ni + 2] = __builtin_amdgcn_mfma_f32_16x16x32_bf16(a47[mi][0], b23[ni][0], acc[mi + 4][ni + 2], 0, 0, 0);
        acc[mi + 4][ni + 2] = __builtin_amdgcn_mfma_f32_16x16x32_bf16(a47[mi][1], b23[ni][1], acc[mi + 4][ni + 2], 0, 0, 0);
      }
    __builtin_amdgcn_s_setprio(0);
  }

  // C/D layout: col=lane&15, row=(lane>>4)*4+reg
  const int cc = lane & 15, cq = lane >> 4;
#pragma unroll
  for (int mi = 0; mi < 8; ++mi) {
#pragma unroll
    for (int ni = 0; ni < 4; ++ni) {
      const int gcol = bn0 + wn + ni * 16 + cc;
      const float bv = bias[gcol];
#pragma unroll
      for (int rr = 0; rr < 4; ++rr) {
        const int grow = bm0 + wm + mi * 16 + cq * 4 + rr;
        C[(size_t)grow * N + gcol] = (__bf16)(acc[mi][ni][rr] + bv);
      }
    }
  }
}

// C[M,N] = A[M,K] @ W[N,K]^T + bias[N]; m97 128x128 structure (kept for the
// small out-proj GEMM where 256 blocks > 64 blocks of the 256-tile).
template <typename TOUT>
__global__ __launch_bounds__(256) void gemm_async(
    const __bf16* __restrict__ A, const __bf16* __restrict__ W,
    const float* __restrict__ bias, TOUT* __restrict__ C,
    int M, int N, int K)
{
  __shared__ __bf16 lA[4096];   // 128 x 32
  __shared__ __bf16 lB[4096];
  const int t = threadIdx.x;
  const int lane = t & 63;
  const int wave = t >> 6;
  const int bm0 = blockIdx.x * 128;
  const int bn0 = blockIdx.y * 128;
  const int wm = (wave >> 1) * 64;
  const int wn = (wave & 1) * 64;

  f32x4 acc[4][4] = {};

  const __bf16* Ap0 = A + (size_t)(bm0 + (t >> 2)) * K + (t & 3) * 8;
  const __bf16* Bp0 = W + (size_t)(bn0 + (t >> 2)) * K + (t & 3) * 8;
  const size_t r64 = (size_t)64 * K;

  for (int k0 = 0; k0 < K; k0 += 32) {
    __syncthreads();
    gl16(Ap0 + k0,       lA + t * 8);
    gl16(Ap0 + r64 + k0, lA + (t + 256) * 8);
    gl16(Bp0 + k0,       lB + t * 8);
    gl16(Bp0 + r64 + k0, lB + (t + 256) * 8);
    __syncthreads();

    const int r = lane & 15, q = lane >> 4;
    bf16x8 af[4], bfr[4];
#pragma unroll
    for (int mi = 0; mi < 4; ++mi) af[mi] = ((const bf16x8*)lA)[(wm + mi * 16 + r) * 4 + q];
#pragma unroll
    for (int ni = 0; ni < 4; ++ni) bfr[ni] = ((const bf16x8*)lB)[(wn + ni * 16 + r) * 4 + q];
#pragma unroll
    for (int mi = 0; mi < 4; ++mi)
#pragma unroll
      for (int ni = 0; ni < 4; ++ni)
        acc[mi][ni] = __builtin_amdgcn_mfma_f32_16x16x32_bf16(af[mi], bfr[ni], acc[mi][ni], 0, 0, 0);
  }

  const int cc = lane & 15, cq = lane >> 4;
#pragma unroll
  for (int mi = 0; mi < 4; ++mi) {
#pragma unroll
    for (int ni = 0; ni < 4; ++ni) {
      const int gcol = bn0 + wn + ni * 16 + cc;
      const float bv = bias[gcol];
#pragma unroll
      for (int rr = 0; rr < 4; ++rr) {
        const int grow = bm0 + wm + mi * 16 + cq * 4 + rr;
        C[(size_t)grow * N + gcol] = (TOUT)(acc[mi][ni][rr] + bv);
      }
    }
  }
}

// Flash-style MFMA attention (r1 green): swizzled lK, reg softmax, 2 barriers.
#define SP 72
#define QS 2048
__global__ __launch_bounds__(256) void attn_tile(
    const __bf16* __restrict__ qu,   // [B*L][2048]  q|k|v|u
    __bf16* __restrict__ g)          // [B*L][512]
{
  const int qt = blockIdx.x, h = blockIdx.y, b = blockIdx.z;
  const int t = threadIdx.x;
  const int lane = t & 63;
  const int w = t >> 6;
  const int q0 = qt * 64, qmax = q0 + 63;
  const size_t bL = (size_t)b * L_;

  __shared__ __bf16 lK[4096];       // [64][64] bf16, XOR-swizzled rows
  __shared__ __bf16 lV[64 * SP];    // V^T: [d 64][key 64] stride 72
  __shared__ __bf16 Pb[64 * SP];    // P:   [q 64][key 64] stride 72 (wave-local)

  const int cq = lane >> 4, cc = lane & 15;

  bf16x8 aq0, aq1;
  {
    const __bf16* qsrc = qu + (bL + q0 + w * 16 + cc) * QS + h * 64 + cq * 8;
    aq0 = *(const bf16x8*)qsrc;
    aq1 = *(const bf16x8*)(qsrc + 32);
  }

  float mreg[4], lreg[4];
#pragma unroll
  for (int rr = 0; rr < 4; ++rr) { mreg[rr] = -1e30f; lreg[rr] = 0.f; }
  f32x4 acc_o[4] = {};

  int clist[5]; int ncl = 0;
  clist[ncl++] = 0;
  if (qmax >= 64) clist[ncl++] = 64;
  {
    int lo = 1921 - q0; if (lo < 0) lo = 0; lo &= ~63;
    const int hik = min(qmax, 2048 - q0);
    for (int c = lo; c <= hik; c += 64)
      if (c >= 128) clist[ncl++] = c;
  }

  for (int ci = 0; ci < ncl; ++ci) {
    const int c0 = clist[ci];
    __syncthreads();
    {
      const int row = t >> 2, gb = t & 3;
      const __bf16* src = qu + (bL + c0 + row) * QS + 512 + h * 64;
      bf16x8 k0 = *(const bf16x8*)(src + gb * 8);
      bf16x8 k1 = *(const bf16x8*)(src + gb * 8 + 32);
      char* lkb = (char*)lK;
      const int sw = (row & 7) << 4;
      *(bf16x8*)(lkb + ((row * 128 + gb * 16) ^ sw))      = k0;
      *(bf16x8*)(lkb + ((row * 128 + gb * 16 + 64) ^ sw)) = k1;
    }
    {
      const int key = lane;
      const __bf16* src = qu + (bL + c0 + key) * QS + 1024 + h * 64 + w * 16;
      bf16x8 va = *(const bf16x8*)src;
      bf16x8 vb = *(const bf16x8*)(src + 8);
#pragma unroll
      for (int e = 0; e < 8; ++e) {
        lV[(w * 16 + e) * SP + key]     = va[e];
        lV[(w * 16 + 8 + e) * SP + key] = vb[e];
      }
    }
    __syncthreads();

    f32x4 s[4];
    {
      const char* lkb = (const char*)lK;
#pragma unroll
      for (int nt = 0; nt < 4; ++nt) {
        const int krow = nt * 16 + cc;
        const int sw = (krow & 7) << 4;
        bf16x8 bk0 = *(const bf16x8*)(lkb + ((krow * 128 + cq * 16) ^ sw));
        bf16x8 bk1 = *(const bf16x8*)(lkb + ((krow * 128 + 64 + cq * 16) ^ sw));
        f32x4 a = {};
        a = __builtin_amdgcn_mfma_f32_16x16x32_bf16(aq0, bk0, a, 0, 0, 0);
        a = __builtin_amdgcn_mfma_f32_16x16x32_bf16(aq1, bk1, a, 0, 0, 0);
        s[nt] = a;
      }
    }

#pragma unroll
    for (int nt = 0; nt < 4; ++nt) {
#pragma unroll
      for (int rr = 0; rr < 4; ++rr) {
        const int i = q0 + w * 16 + cq * 4 + rr;
        const int j = c0 + nt * 16 + cc;
        const int ij = i + j;
        const bool valid = (j <= i) &&
            ((ij >= 1984 && ij <= 2048) || (j <= 64 && ij <= 2048));
        s[nt][rr] = valid ? s[nt][rr] * 0.125f : -1e30f;
      }
    }

    f32x4 pm;
#pragma unroll
    for (int rr = 0; rr < 4; ++rr)
      pm[rr] = fmaxf(fmaxf(s[0][rr], s[1][rr]), fmaxf(s[2][rr], s[3][rr]));
#pragma unroll
    for (int m = 1; m < 16; m <<= 1) {
#pragma unroll
      for (int rr = 0; rr < 4; ++rr)
        pm[rr] = fmaxf(pm[rr], __shfl_xor(pm[rr], m, 64));
    }
    float corr[4];
#pragma unroll
    for (int rr = 0; rr < 4; ++rr) {
      const float nm = fmaxf(mreg[rr], pm[rr]);
      corr[rr] = __expf(mreg[rr] - nm);
      mreg[rr] = nm;
    }

    f32x4 ps = {};
#pragma unroll
    for (int nt = 0; nt < 4; ++nt) {
#pragma unroll
      for (int rr = 0; rr < 4; ++rr) {
        const float p = __expf(s[nt][rr] - mreg[rr]);
        ps[rr] += p;
        Pb[(w * 16 + cq * 4 + rr) * SP + nt * 16 + cc] = (__bf16)p;
      }
    }
#pragma unroll
    for (int m = 1; m < 16; m <<= 1) {
#pragma unroll
      for (int rr = 0; rr < 4; ++rr)
        ps[rr] += __shfl_xor(ps[rr], m, 64);
    }
#pragma unroll
    for (int rr = 0; rr < 4; ++rr) lreg[rr] = lreg[rr] * corr[rr] + ps[rr];

    {
      bf16x8 pa0 = *(const bf16x8*)(Pb + (w * 16 + cc) * SP + cq * 8);
      bf16x8 pa1 = *(const bf16x8*)(Pb + (w * 16 + cc) * SP + 32 + cq * 8);
#pragma unroll
      for (int dt = 0; dt < 4; ++dt) {
#pragma unroll
        for (int rr = 0; rr < 4; ++rr) acc_o[dt][rr] *= corr[rr];
        bf16x8 vb0 = *(const bf16x8*)(lV + (dt * 16 + cc) * SP + cq * 8);
        bf16x8 vb1 = *(const bf16x8*)(lV + (dt * 16 + cc) * SP + 32 + cq * 8);
        acc_o[dt] = __builtin_amdgcn_mfma_f32_16x16x32_bf16(pa0, vb0, acc_o[dt], 0, 0, 0);
        acc_o[dt] = __builtin_amdgcn_mfma_f32_16x16x32_bf16(pa1, vb1, acc_o[dt], 0, 0, 0);
      }
    }
  }

#pragma unroll
  for (int dt = 0; dt < 4; ++dt) {
#pragma unroll
    for (int rr = 0; rr < 4; ++rr) {
      const int row16 = cq * 4 + rr;
      const size_t qrow = bL + q0 + w * 16 + row16;
      const int d = dt * 16 + cc;
      const float o = acc_o[dt][rr] / fmaxf(lreg[rr], 1e-30f);
      const float uv = (float)qu[qrow * QS + 1536 + h * 64 + d];
      g[qrow * D_ + h * 64 + d] = (__bf16)(o / (1.f + __expf(-o)) * uv);
    }
  }
}

extern "C" void kernel_launch(void* const* d_in, const int* in_sizes, int n_in,
                              void* d_out, int out_size, void* d_ws, size_t ws_size,
                              hipStream_t stream) {
  const float* x     = (const float*)d_in[0];
  const float* w_qkv = (const float*)d_in[1];
  const float* b_qkv = (const float*)d_in[2];
  const float* w_u   = (const float*)d_in[3];
  const float* b_u   = (const float*)d_in[4];
  const float* w_out = (const float*)d_in[5];
  const float* b_out = (const float*)d_in[6];
  float* out = (float*)d_out;

  char* ws = (char*)d_ws;
  __bf16* xb   = (__bf16*)ws;                           //  8 MB
  __bf16* wcat = (__bf16*)(ws + 8388608);               //  2 MB [w_qkv;w_u]
  __bf16* wob  = (__bf16*)(ws + 10485760);              //  0.5 MB
  float*  bcat = (float*) (ws + 11010048);              //  8 KB
  __bf16* qu   = (__bf16*)(ws + 11018240);              // 32 MB [q|k|v|u]
  __bf16* gb   = (__bf16*)(ws + 44572672);              //  8 MB

  // one-time opt-in for 128 KB dynamic LDS (host-side attr, graph-safe)
  static bool attr_done = []() {
    hipFuncSetAttribute((const void*)gemm256,
                        hipFuncAttributeMaxDynamicSharedMemorySize, 131072);
    return true;
  }();
  (void)attr_done;

  cvt_pack<<<dim3(2688), dim3(256), 0, stream>>>(
      x, w_qkv, w_u, w_out, b_qkv, b_u, xb, wcat, wob, bcat);
  gemm256<<<dim3(32, 8), dim3(512), 131072, stream>>>(
      xb, wcat, bcat, qu, 8192, 2048, 512);
  attn_tile<<<dim3(L_ / 64, H_, B_), dim3(256), 0, stream>>>(qu, gb);
  gemm_async<float><<<dim3(64, 4), dim3(256), 0, stream>>>(
      gb, wob, b_out, out, 8192, 512, 512);
}

// Round 3
// 148.350 us; speedup vs baseline: 1.1098x; 1.0011x over previous
//
#include <hip/hip_runtime.h>
#include <hip/hip_bf16.h>

typedef __bf16 bf16x8 __attribute__((ext_vector_type(8)));
typedef float f32x4 __attribute__((ext_vector_type(4)));

#define B_ 4
#define L_ 2048
#define D_ 512
#define H_ 8

// async 16B global -> LDS (gfx950 global_load_lds_dwordx4)
__device__ __forceinline__ void gl16(const __bf16* g, __bf16* l) {
  __builtin_amdgcn_global_load_lds(
      (const __attribute__((address_space(1))) void*)g,
      (__attribute__((address_space(3))) void*)l, 16, 0, 0);
}

// f32 -> bf16 conversion + packing. vec8 regions:
// x[0,524288) wqkv[524288,622592) wu[622592,655360) wout[655360,688128)
// Also builds bcat[2048] = [b_qkv ; b_u] (f32) in block 0.
__global__ __launch_bounds__(256) void cvt_pack(
    const float* __restrict__ x, const float* __restrict__ wq,
    const float* __restrict__ wu, const float* __restrict__ wo,
    const float* __restrict__ bq, const float* __restrict__ bu,
    __bf16* __restrict__ xb, __bf16* __restrict__ wcat,
    __bf16* __restrict__ wob, float* __restrict__ bcat)
{
  const int idx8 = blockIdx.x * 256 + threadIdx.x;
  const float* src; __bf16* dst; size_t so, dof;
  if (idx8 < 524288)      { src = x;  dst = xb;   so = (size_t)idx8 * 8;            dof = so; }
  else if (idx8 < 622592) { src = wq; dst = wcat; so = (size_t)(idx8 - 524288) * 8; dof = so; }
  else if (idx8 < 655360) { src = wu; dst = wcat; so = (size_t)(idx8 - 622592) * 8; dof = so + 786432; }
  else                    { src = wo; dst = wob;  so = (size_t)(idx8 - 655360) * 8; dof = so; }
  const float4 lo = *(const float4*)(src + so);
  const float4 hi = *(const float4*)(src + so + 4);
  bf16x8 r;
  r[0] = (__bf16)lo.x; r[1] = (__bf16)lo.y; r[2] = (__bf16)lo.z; r[3] = (__bf16)lo.w;
  r[4] = (__bf16)hi.x; r[5] = (__bf16)hi.y; r[6] = (__bf16)hi.z; r[7] = (__bf16)hi.w;
  *(bf16x8*)(dst + dof) = r;
  if (blockIdx.x == 0) {
#pragma unroll
    for (int e = 0; e < 8; ++e) {
      const int col = threadIdx.x * 8 + e;
      bcat[col] = (col < 1536) ? bq[col] : bu[col - 1536];
    }
  }
}

// ---------------------------------------------------------------------------
// 256x256 deep-pipelined GEMM, m201-exact phase brackets (T2+T3+T4+T5).
// C[M,N] = A[M,K] @ W[N,K]^T + bias[N], bf16 out. 512 thr = 8 waves (2Mx4N),
// per-wave 128x64 out. LDS 128 KB dynamic (2 bufs x (A 32K + B 32K)).
//
// Per K-tile t (buf p=t&1), 4 phases, each bracketed
//   {ds_reads; s_barrier; lgkmcnt(0); prio1 16xMFMA prio0; s_barrier}:
//   entry: vmcnt(8) [vmcnt(0) last tile]; s_barrier      (RAW: buf p landed)
//   ph0: read A03x2k (8 b128) + B01x2k (4)  | MFMA A03xB01
//   ph1: read B23x2k (4)                    | MFMA A03xB23
//   ph2: read A47x2k (8)                    | MFMA A47xB01
//        (closing barrier = WAR: all reads of buf p retired by all waves)
//   ph3: stage tile t+2 -> buf p (8 gl16)   | MFMA A47xB23 (regs only)
// vmcnt never drains to 0 mid-loop: 16 loads in flight steady-state.
//
// LDS swizzle (T2): byte ^= (row&7)<<4 on reads; global source pre-permuted
// with the same involution (c_src = c ^ ((c>>3)&7)) since global_load_lds
// writes linearly (both-sides-or-neither rule).
// ---------------------------------------------------------------------------
__global__ __launch_bounds__(512, 2) void gemm256(
    const __bf16* __restrict__ A, const __bf16* __restrict__ W,
    const float* __restrict__ bias, __bf16* __restrict__ C,
    int M, int N, int K)
{
  extern __shared__ char smem[];
  const int t = threadIdx.x;
  const int lane = t & 63;
  const int wave = t >> 6;
  const int wm = (wave >> 2) * 128;
  const int wn = (wave & 3) * 64;
  const int bm0 = blockIdx.x * 256;
  const int bn0 = blockIdx.y * 256;
  const int r = lane & 15, q = lane >> 4;
  const int nt = K >> 6;

  auto stage = [&](int kt, int p) {
#pragma unroll
    for (int j = 0; j < 4; ++j) {
      const int c = t + j * 512;
      const int row = c >> 3;
      const int cs = (c & 7) ^ (row & 7);
      gl16(A + (size_t)(bm0 + row) * K + kt * 64 + cs * 8,
           (__bf16*)(smem + p * 32768) + c * 8);
    }
#pragma unroll
    for (int j = 0; j < 4; ++j) {
      const int c = t + j * 512;
      const int row = c >> 3;
      const int cs = (c & 7) ^ (row & 7);
      gl16(W + (size_t)(bn0 + row) * K + kt * 64 + cs * 8,
           (__bf16*)(smem + 65536 + p * 32768) + c * 8);
    }
  };
  auto rdA = [&](int p, int mi, int ks) -> bf16x8 {
    const int row = wm + mi * 16 + r;
    const int byte = row * 128 + ((ks * 64 + q * 16) ^ ((row & 7) << 4));
    return *(const bf16x8*)(smem + p * 32768 + byte);
  };
  auto rdB = [&](int p, int ni, int ks) -> bf16x8 {
    const int row = wn + ni * 16 + r;
    const int byte = row * 128 + ((ks * 64 + q * 16) ^ ((row & 7) << 4));
    return *(const bf16x8*)(smem + 65536 + p * 32768 + byte);
  };

#define SB0 __builtin_amdgcn_sched_barrier(0)
#define LGKM0 asm volatile("s_waitcnt lgkmcnt(0)" ::: "memory")

  f32x4 acc[8][4] = {};

  stage(0, 0);
  stage(1, 1);

  for (int kt = 0; kt < nt; ++kt) {
    const int p = kt & 1;
    // ---- entry (RAW): tile kt staged & visible ----
    if (kt < nt - 1) asm volatile("s_waitcnt vmcnt(8)" ::: "memory");
    else             asm volatile("s_waitcnt vmcnt(0)" ::: "memory");
    SB0;
    __builtin_amdgcn_s_barrier();
    SB0;

    bf16x8 a03[4][2], a47[4][2], b01[2][2], b23[2][2];
    // ---- ph0: A03 + B01 ----
#pragma unroll
    for (int mi = 0; mi < 4; ++mi) { a03[mi][0] = rdA(p, mi, 0); a03[mi][1] = rdA(p, mi, 1); }
#pragma unroll
    for (int ni = 0; ni < 2; ++ni) { b01[ni][0] = rdB(p, ni, 0); b01[ni][1] = rdB(p, ni, 1); }
    SB0; __builtin_amdgcn_s_barrier(); LGKM0; SB0;
    __builtin_amdgcn_s_setprio(1);
#pragma unroll
    for (int mi = 0; mi < 4; ++mi)
#pragma unroll
      for (int ni = 0; ni < 2; ++ni) {
        acc[mi][ni] = __builtin_amdgcn_mfma_f32_16x16x32_bf16(a03[mi][0], b01[ni][0], acc[mi][ni], 0, 0, 0);
        acc[mi][ni] = __builtin_amdgcn_mfma_f32_16x16x32_bf16(a03[mi][1], b01[ni][1], acc[mi][ni], 0, 0, 0);
      }
    __builtin_amdgcn_s_setprio(0);
    SB0; __builtin_amdgcn_s_barrier(); SB0;
    // ---- ph1: B23 ----
#pragma unroll
    for (int ni = 0; ni < 2; ++ni) { b23[ni][0] = rdB(p, ni + 2, 0); b23[ni][1] = rdB(p, ni + 2, 1); }
    SB0; __builtin_amdgcn_s_barrier(); LGKM0; SB0;
    __builtin_amdgcn_s_setprio(1);
#pragma unroll
    for (int mi = 0; mi < 4; ++mi)
#pragma unroll
      for (int ni = 0; ni < 2; ++ni) {
        acc[mi][ni + 2] = __builtin_amdgcn_mfma_f32_16x16x32_bf16(a03[mi][0], b23[ni][0], acc[mi][ni + 2], 0, 0, 0);
        acc[mi][ni + 2] = __builtin_amdgcn_mfma_f32_16x16x32_bf16(a03[mi][1], b23[ni][1], acc[mi][ni + 2], 0, 0, 0);
      }
    __builtin_amdgcn_s_setprio(0);
    SB0; __builtin_amdgcn_s_barrier(); SB0;
    // ---- ph2: A47 ----
#pragma unroll
    for (int mi = 0; mi < 4; ++mi) { a47[mi][0] = rdA(p, mi + 4, 0); a47[mi][1] = rdA(p, mi + 4, 1); }
    SB0; __builtin_amdgcn_s_barrier(); LGKM0; SB0;
    __builtin_amdgcn_s_setprio(1);
#pragma unroll
    for (int mi = 0; mi < 4; ++mi)
#pragma unroll
      for (int ni = 0; ni < 2; ++ni) {
        acc[mi + 4][ni] = __builtin_amdgcn_mfma_f32_16x16x32_bf16(a47[mi][0], b01[ni][0], acc[mi + 4][ni], 0, 0, 0);
        acc[mi + 4][ni] = __builtin_amdgcn_mfma_f32_16x16x32_bf16(a47[mi][1], b01[ni][1], acc[mi + 4][ni], 0, 0, 0);
      }
    __builtin_amdgcn_s_setprio(0);
    // closing barrier of ph2 = WAR point: every wave has lgkm-retired all
    // of its buf-p reads (ph0/ph1/ph2) before passing it.
    SB0; __builtin_amdgcn_s_barrier(); SB0;
    // ---- ph3: stage kt+2 (overlaps MFMA; counted at next entries) ----
    if (kt + 2 < nt) stage(kt + 2, p);
    __builtin_amdgcn_s_setprio(1);
#pragma unroll
    for (int mi = 0; mi < 4; ++mi)
#pragma unroll
      for (int ni = 0; ni < 2; ++ni) {
        acc[mi + 4][ni + 2] = __builtin_amdgcn_mfma_f32_16x16x32_bf16(a47[mi][0], b23[ni][0], acc[mi + 4][ni + 2], 0, 0, 0);
        acc[mi + 4][ni + 2] = __builtin_amdgcn_mfma_f32_16x16x32_bf16(a47[mi][1], b23[ni][1], acc[mi + 4][ni + 2], 0, 0, 0);
      }
    __builtin_amdgcn_s_setprio(0);
  }

  // C/D layout: col=lane&15, row=(lane>>4)*4+reg
  const int cc = lane & 15, cq = lane >> 4;
#pragma unroll
  for (int mi = 0; mi < 8; ++mi) {
#pragma unroll
    for (int ni = 0; ni < 4; ++ni) {
      const int gcol = bn0 + wn + ni * 16 + cc;
      const float bv = bias[gcol];
#pragma unroll
      for (int rr = 0; rr < 4; ++rr) {
        const int grow = bm0 + wm + mi * 16 + cq * 4 + rr;
        C[(size_t)grow * N + gcol] = (__bf16)(acc[mi][ni][rr] + bv);
      }
    }
  }
}

// C[M,N] = A[M,K] @ W[N,K]^T + bias[N]; m97 128x128 structure (out-proj:
// N=512 keeps grid at 256 blocks here vs 64 for the 256-tile).
template <typename TOUT>
__global__ __launch_bounds__(256) void gemm_async(
    const __bf16* __restrict__ A, const __bf16* __restrict__ W,
    const float* __restrict__ bias, TOUT* __restrict__ C,
    int M, int N, int K)
{
  __shared__ __bf16 lA[4096];   // 128 x 32
  __shared__ __bf16 lB[4096];
  const int t = threadIdx.x;
  const int lane = t & 63;
  const int wave = t >> 6;
  const int bm0 = blockIdx.x * 128;
  const int bn0 = blockIdx.y * 128;
  const int wm = (wave >> 1) * 64;
  const int wn = (wave & 1) * 64;

  f32x4 acc[4][4] = {};

  const __bf16* Ap0 = A + (size_t)(bm0 + (t >> 2)) * K + (t & 3) * 8;
  const __bf16* Bp0 = W + (size_t)(bn0 + (t >> 2)) * K + (t & 3) * 8;
  const size_t r64 = (size_t)64 * K;

  for (int k0 = 0; k0 < K; k0 += 32) {
    __syncthreads();
    gl16(Ap0 + k0,       lA + t * 8);
    gl16(Ap0 + r64 + k0, lA + (t + 256) * 8);
    gl16(Bp0 + k0,       lB + t * 8);
    gl16(Bp0 + r64 + k0, lB + (t + 256) * 8);
    __syncthreads();

    const int r = lane & 15, q = lane >> 4;
    bf16x8 af[4], bfr[4];
#pragma unroll
    for (int mi = 0; mi < 4; ++mi) af[mi] = ((const bf16x8*)lA)[(wm + mi * 16 + r) * 4 + q];
#pragma unroll
    for (int ni = 0; ni < 4; ++ni) bfr[ni] = ((const bf16x8*)lB)[(wn + ni * 16 + r) * 4 + q];
#pragma unroll
    for (int mi = 0; mi < 4; ++mi)
#pragma unroll
      for (int ni = 0; ni < 4; ++ni)
        acc[mi][ni] = __builtin_amdgcn_mfma_f32_16x16x32_bf16(af[mi], bfr[ni], acc[mi][ni], 0, 0, 0);
  }

  const int cc = lane & 15, cq = lane >> 4;
#pragma unroll
  for (int mi = 0; mi < 4; ++mi) {
#pragma unroll
    for (int ni = 0; ni < 4; ++ni) {
      const int gcol = bn0 + wn + ni * 16 + cc;
      const float bv = bias[gcol];
#pragma unroll
      for (int rr = 0; rr < 4; ++rr) {
        const int grow = bm0 + wm + mi * 16 + cq * 4 + rr;
        C[(size_t)grow * N + gcol] = (TOUT)(acc[mi][ni][rr] + bv);
      }
    }
  }
}

// Flash-style MFMA attention: swizzled lK, reg softmax, T14 async-stage.
// Per tile: {vmcnt(0); s_barrier(WAR); ds_write K,V; issue next K/V global
// loads; lgkmcnt(0); s_barrier(RAW); compute} -- next tile's HBM/L3 latency
// hides under this tile's QK/softmax/PV. Raw barriers + explicit per-wave
// waitcnts (a __syncthreads here would drain vmcnt and kill the overlap).
#define SP 72
#define QS 2048
__global__ __launch_bounds__(256) void attn_tile(
    const __bf16* __restrict__ qu,   // [B*L][2048]  q|k|v|u
    __bf16* __restrict__ g)          // [B*L][512]
{
  const int qt = blockIdx.x, h = blockIdx.y, b = blockIdx.z;
  const int t = threadIdx.x;
  const int lane = t & 63;
  const int w = t >> 6;
  const int q0 = qt * 64, qmax = q0 + 63;
  const size_t bL = (size_t)b * L_;

  __shared__ __bf16 lK[4096];       // [64][64] bf16, XOR-swizzled rows
  __shared__ __bf16 lV[64 * SP];    // V^T: [d 64][key 64] stride 72
  __shared__ __bf16 Pb[64 * SP];    // P:   [q 64][key 64] stride 72 (wave-local)

  const int cq = lane >> 4, cc = lane & 15;
  const int krow_st = t >> 2, kgb = t & 3;   // K-staging coords

  bf16x8 aq0, aq1;
  {
    const __bf16* qsrc = qu + (bL + q0 + w * 16 + cc) * QS + h * 64 + cq * 8;
    aq0 = *(const bf16x8*)qsrc;
    aq1 = *(const bf16x8*)(qsrc + 32);
  }

  float mreg[4], lreg[4];
#pragma unroll
  for (int rr = 0; rr < 4; ++rr) { mreg[rr] = -1e30f; lreg[rr] = 0.f; }
  f32x4 acc_o[4] = {};

  int clist[5]; int ncl = 0;
  clist[ncl++] = 0;
  if (qmax >= 64) clist[ncl++] = 64;
  {
    int lo = 1921 - q0; if (lo < 0) lo = 0; lo &= ~63;
    const int hik = min(qmax, 2048 - q0);
    for (int c = lo; c <= hik; c += 64)
      if (c >= 128) clist[ncl++] = c;
  }

  // prologue: issue tile-0 K/V loads into registers
  bf16x8 k0r, k1r, var, vbr;
  {
    const __bf16* src = qu + (bL + clist[0] + krow_st) * QS + 512 + h * 64;
    k0r = *(const bf16x8*)(src + kgb * 8);
    k1r = *(const bf16x8*)(src + kgb * 8 + 32);
    const __bf16* vsrc = qu + (bL + clist[0] + lane) * QS + 1024 + h * 64 + w * 16;
    var = *(const bf16x8*)vsrc;
    vbr = *(const bf16x8*)(vsrc + 8);
  }

  for (int ci = 0; ci < ncl; ++ci) {
    const int c0 = clist[ci];
    asm volatile("s_waitcnt vmcnt(0)" ::: "memory");   // this tile's K/V landed
    __builtin_amdgcn_sched_barrier(0);
    __builtin_amdgcn_s_barrier();                      // WAR: prior tile's reads done
    __builtin_amdgcn_sched_barrier(0);
    {  // ds_write K (swizzled) + V^T (scalar transpose writes, conflict-free)
      char* lkb = (char*)lK;
      const int sw = (krow_st & 7) << 4;
      *(bf16x8*)(lkb + ((krow_st * 128 + kgb * 16) ^ sw))      = k0r;
      *(bf16x8*)(lkb + ((krow_st * 128 + kgb * 16 + 64) ^ sw)) = k1r;
#pragma unroll
      for (int e = 0; e < 8; ++e) {
        lV[(w * 16 + e) * SP + lane]     = var[e];
        lV[(w * 16 + 8 + e) * SP + lane] = vbr[e];
      }
    }
    // issue NEXT tile's global loads (in flight across this tile's compute)
    if (ci + 1 < ncl) {
      const int cn = clist[ci + 1];
      const __bf16* src = qu + (bL + cn + krow_st) * QS + 512 + h * 64;
      k0r = *(const bf16x8*)(src + kgb * 8);
      k1r = *(const bf16x8*)(src + kgb * 8 + 32);
      const __bf16* vsrc = qu + (bL + cn + lane) * QS + 1024 + h * 64 + w * 16;
      var = *(const bf16x8*)(vsrc);
      vbr = *(const bf16x8*)(vsrc + 8);
    }
    asm volatile("s_waitcnt lgkmcnt(0)" ::: "memory"); // my ds_writes retired
    __builtin_amdgcn_sched_barrier(0);
    __builtin_amdgcn_s_barrier();                      // RAW: all writes visible
    __builtin_amdgcn_sched_barrier(0);

    f32x4 s[4];
    {
      const char* lkb = (const char*)lK;
#pragma unroll
      for (int nt = 0; nt < 4; ++nt) {
        const int krow = nt * 16 + cc;
        const int sw = (krow & 7) << 4;
        bf16x8 bk0 = *(const bf16x8*)(lkb + ((krow * 128 + cq * 16) ^ sw));
        bf16x8 bk1 = *(const bf16x8*)(lkb + ((krow * 128 + 64 + cq * 16) ^ sw));
        f32x4 a = {};
        a = __builtin_amdgcn_mfma_f32_16x16x32_bf16(aq0, bk0, a, 0, 0, 0);
        a = __builtin_amdgcn_mfma_f32_16x16x32_bf16(aq1, bk1, a, 0, 0, 0);
        s[nt] = a;
      }
    }

#pragma unroll
    for (int nt = 0; nt < 4; ++nt) {
#pragma unroll
      for (int rr = 0; rr < 4; ++rr) {
        const int i = q0 + w * 16 + cq * 4 + rr;
        const int j = c0 + nt * 16 + cc;
        const int ij = i + j;
        const bool valid = (j <= i) &&
            ((ij >= 1984 && ij <= 2048) || (j <= 64 && ij <= 2048));
        s[nt][rr] = valid ? s[nt][rr] * 0.125f : -1e30f;
      }
    }

    f32x4 pm;
#pragma unroll
    for (int rr = 0; rr < 4; ++rr)
      pm[rr] = fmaxf(fmaxf(s[0][rr], s[1][rr]), fmaxf(s[2][rr], s[3][rr]));
#pragma unroll
    for (int m = 1; m < 16; m <<= 1) {
#pragma unroll
      for (int rr = 0; rr < 4; ++rr)
        pm[rr] = fmaxf(pm[rr], __shfl_xor(pm[rr], m, 64));
    }
    float corr[4];
#pragma unroll
    for (int rr = 0; rr < 4; ++rr) {
      const float nm = fmaxf(mreg[rr], pm[rr]);
      corr[rr] = __expf(mreg[rr] - nm);
      mreg[rr] = nm;
    }

    f32x4 ps = {};
#pragma unroll
    for (int nt = 0; nt < 4; ++nt) {
#pragma unroll
      for (int rr = 0; rr < 4; ++rr) {
        const float p = __expf(s[nt][rr] - mreg[rr]);
        ps[rr] += p;
        Pb[(w * 16 + cq * 4 + rr) * SP + nt * 16 + cc] = (__bf16)p;
      }
    }
#pragma unroll
    for (int m = 1; m < 16; m <<= 1) {
#pragma unroll
      for (int rr = 0; rr < 4; ++rr)
        ps[rr] += __shfl_xor(ps[rr], m, 64);
    }
#pragma unroll
    for (int rr = 0; rr < 4; ++rr) lreg[rr] = lreg[rr] * corr[rr] + ps[rr];

    {
      bf16x8 pa0 = *(const bf16x8*)(Pb + (w * 16 + cc) * SP + cq * 8);
      bf16x8 pa1 = *(const bf16x8*)(Pb + (w * 16 + cc) * SP + 32 + cq * 8);
#pragma unroll
      for (int dt = 0; dt < 4; ++dt) {
#pragma unroll
        for (int rr = 0; rr < 4; ++rr) acc_o[dt][rr] *= corr[rr];
        bf16x8 vb0 = *(const bf16x8*)(lV + (dt * 16 + cc) * SP + cq * 8);
        bf16x8 vb1 = *(const bf16x8*)(lV + (dt * 16 + cc) * SP + 32 + cq * 8);
        acc_o[dt] = __builtin_amdgcn_mfma_f32_16x16x32_bf16(pa0, vb0, acc_o[dt], 0, 0, 0);
        acc_o[dt] = __builtin_amdgcn_mfma_f32_16x16x32_bf16(pa1, vb1, acc_o[dt], 0, 0, 0);
      }
    }
  }

  // epilogue: register state only (no LDS) -> no barrier needed
#pragma unroll
  for (int dt = 0; dt < 4; ++dt) {
#pragma unroll
    for (int rr = 0; rr < 4; ++rr) {
      const int row16 = cq * 4 + rr;
      const size_t qrow = bL + q0 + w * 16 + row16;
      const int d = dt * 16 + cc;
      const float o = acc_o[dt][rr] / fmaxf(lreg[rr], 1e-30f);
      const float uv = (float)qu[qrow * QS + 1536 + h * 64 + d];
      g[qrow * D_ + h * 64 + d] = (__bf16)(o / (1.f + __expf(-o)) * uv);
    }
  }
}

extern "C" void kernel_launch(void* const* d_in, const int* in_sizes, int n_in,
                              void* d_out, int out_size, void* d_ws, size_t ws_size,
                              hipStream_t stream) {
  const float* x     = (const float*)d_in[0];
  const float* w_qkv = (const float*)d_in[1];
  const float* b_qkv = (const float*)d_in[2];
  const float* w_u   = (const float*)d_in[3];
  const float* b_u   = (const float*)d_in[4];
  const float* w_out = (const float*)d_in[5];
  const float* b_out = (const float*)d_in[6];
  float* out = (float*)d_out;

  char* ws = (char*)d_ws;
  __bf16* xb   = (__bf16*)ws;                           //  8 MB
  __bf16* wcat = (__bf16*)(ws + 8388608);               //  2 MB [w_qkv;w_u]
  __bf16* wob  = (__bf16*)(ws + 10485760);              //  0.5 MB
  float*  bcat = (float*) (ws + 11010048);              //  8 KB
  __bf16* qu   = (__bf16*)(ws + 11018240);              // 32 MB [q|k|v|u]
  __bf16* gb   = (__bf16*)(ws + 44572672);              //  8 MB

  // one-time opt-in for 128 KB dynamic LDS (host-side attr, graph-safe)
  static bool attr_done = []() {
    hipFuncSetAttribute((const void*)gemm256,
                        hipFuncAttributeMaxDynamicSharedMemorySize, 131072);
    return true;
  }();
  (void)attr_done;

  cvt_pack<<<dim3(2688), dim3(256), 0, stream>>>(
      x, w_qkv, w_u, w_out, b_qkv, b_u, xb, wcat, wob, bcat);
  gemm256<<<dim3(32, 8), dim3(512), 131072, stream>>>(
      xb, wcat, bcat, qu, 8192, 2048, 512);
  attn_tile<<<dim3(L_ / 64, H_, B_), dim3(256), 0, stream>>>(qu, gb);
  gemm_async<float><<<dim3(64, 4), dim3(256), 0, stream>>>(
      gb, wob, b_out, out, 8192, 512, 512);
}